// Round 3
// baseline (362.022 us; speedup 1.0000x reference)
//
#include <hip/hip_runtime.h>

constexpr int Dd = 128, Hh = 128, Ww = 128;
constexpr int B_ = 2, L_ = 8;
constexpr int S_SP = Dd * Hh * Ww;          // 2097152
constexpr float CLAMP_MIN = 0.071f;
constexpr float EPS = 1e-5f;

constexpr int TIL = 16;                     // hw tile
constexpr int HALO = TIL + 2;               // 18
constexpr int DCH = 8;                      // d planes per block (was 16)
constexpr int NPOS = HALO * HALO;           // 324
constexpr int NDC = Dd / DCH;               // 16
constexpr int BLK_PER_B = NDC * (Hh / TIL) * (Ww / TIL);  // 1024
constexpr int NBLK = B_ * BLK_PER_B;        // 2048

__device__ __forceinline__ int refl(int x, int n) {
  return x < 0 ? 1 : (x >= n ? n - 2 : x);
}

__device__ __forceinline__ void halo_load(const float* __restrict__ predb,
                                          int rpd, int h0, int w0, int pos,
                                          float v[L_]) {
  int i = pos / HALO, j = pos - i * HALO;
  int gh = refl(h0 - 1 + i, Hh);
  int gw = refl(w0 - 1 + j, Ww);
  const float* src = predb + (size_t)rpd * Hh * Ww + gh * Ww + gw;
#pragma unroll
  for (int l = 0; l < L_; ++l) v[l] = src[(size_t)l * S_SP];
}

__device__ __forceinline__ void softmax_store(float v[L_], float* dst8) {
  float m = v[0];
#pragma unroll
  for (int l = 1; l < L_; ++l) m = fmaxf(m, v[l]);
  float s = 0.f;
#pragma unroll
  for (int l = 0; l < L_; ++l) { v[l] = __expf(v[l] - m); s += v[l]; }
  float inv = 1.f / s;
#pragma unroll
  for (int l = 0; l < L_; ++l) v[l] = fmaxf(v[l] * inv, CLAMP_MIN);
  float4* dst = (float4*)dst8;
  dst[0] = make_float4(v[0], v[1], v[2], v[3]);
  dst[1] = make_float4(v[4], v[5], v[6], v[7]);
}

// One block: (b, 8-plane d-chunk, 16x16 hw tile), all 8 labels.
// Register-prefetched halo loads; rolling 3x3 plane sums in regs over d.
__global__ __launch_bounds__(256) void fused_kernel(
    const float* __restrict__ pred, const float* __restrict__ tgt,
    float* __restrict__ partial) {
  __shared__ float sps[NPOS][L_];     // 324*8*4 = 10368 B
  __shared__ float red[4][16];

  int blk = blockIdx.x;
  int tw = blk & 7, th = (blk >> 3) & 7, dc = (blk >> 6) & 15, b = blk >> 10;
  int h0 = th * TIL, w0 = tw * TIL, d0 = dc * DCH;
  int tid = threadIdx.x;
  int hl = tid >> 4, wl = tid & 15;
  const float* predb = pred + (size_t)b * L_ * S_SP;
  const bool has2 = (tid + 256) < NPOS;    // threads 0..67 own a second position

  float s2m[L_], s2c[L_], s2n[L_], ctrc[L_], ctrn[L_];
  float atop[L_], abot[L_];
#pragma unroll
  for (int l = 0; l < L_; ++l) { atop[l] = 0.f; abot[l] = 0.f; }

  // prefetch plane pp = -1
  float v0[L_], v1[L_];
  {
    int pd = d0 - 1;
    int rpd = pd < 0 ? 1 : (pd >= Dd ? Dd - 2 : pd);
    halo_load(predb, rpd, h0, w0, tid, v0);
    if (has2) halo_load(predb, rpd, h0, w0, tid + 256, v1);
  }

  for (int pp = -1; pp <= DCH; ++pp) {
    __syncthreads();   // prior plane's stencil reads done
    // ---- softmax+clamp prefetched regs -> LDS ----
    softmax_store(v0, &sps[tid][0]);
    if (has2) softmax_store(v1, &sps[tid + 256][0]);
    // ---- issue next plane's global loads (consumed next iteration) ----
    if (pp + 1 <= DCH) {
      int pdn = d0 + pp + 1;
      int rpdn = pdn < 0 ? 1 : (pdn >= Dd ? Dd - 2 : pdn);
      halo_load(predb, rpdn, h0, w0, tid, v0);
      if (has2) halo_load(predb, rpdn, h0, w0, tid + 256, v1);
    }
    __syncthreads();   // LDS writes visible
    // ---- 3x3 2D sums for this plane (all 8 labels) ----
#pragma unroll
    for (int l = 0; l < L_; ++l) s2n[l] = 0.f;
#pragma unroll
    for (int di = 0; di < 3; ++di) {
#pragma unroll
      for (int dj = 0; dj < 3; ++dj) {
        const float4* q = (const float4*)&sps[(hl + di) * HALO + (wl + dj)][0];
        float4 a = q[0], c4 = q[1];
        s2n[0] += a.x;  s2n[1] += a.y;  s2n[2] += a.z;  s2n[3] += a.w;
        s2n[4] += c4.x; s2n[5] += c4.y; s2n[6] += c4.z; s2n[7] += c4.w;
        if (di == 1 && dj == 1) {
          ctrn[0] = a.x;  ctrn[1] = a.y;  ctrn[2] = a.z;  ctrn[3] = a.w;
          ctrn[4] = c4.x; ctrn[5] = c4.y; ctrn[6] = c4.z; ctrn[7] = c4.w;
        }
      }
    }
    // ---- output plane d = (d0+pp)-1 ----
    if (pp >= 1) {
      int d = d0 + pp - 1;
      size_t off0 = (size_t)b * L_ * S_SP + (size_t)d * Hh * Ww + (h0 + hl) * Ww + (w0 + wl);
#pragma unroll
      for (int l = 0; l < L_; ++l) {
        float sum27 = s2m[l] + s2c[l] + s2n[l];
        float bt = fabsf(27.f * ctrc[l] - sum27);
        float bw = 0.5f / (bt + 0.5f);
        size_t off = off0 + (size_t)l * S_SP;
        float p = pred[off];
        float t = tgt[off];
        atop[l] += t * p * bw;
        abot[l] += (t + p) * bw;
      }
    }
#pragma unroll
    for (int l = 0; l < L_; ++l) { s2m[l] = s2c[l]; s2c[l] = s2n[l]; ctrc[l] = ctrn[l]; }
  }

  // ---- block reduction: 8 labels x (top,bot) ----
#pragma unroll
  for (int l = 0; l < L_; ++l) {
#pragma unroll
    for (int o = 32; o > 0; o >>= 1) {
      atop[l] += __shfl_down(atop[l], o, 64);
      abot[l] += __shfl_down(abot[l], o, 64);
    }
  }
  int lane = tid & 63, wv = tid >> 6;
  if (lane == 0) {
#pragma unroll
    for (int l = 0; l < L_; ++l) { red[wv][l * 2] = atop[l]; red[wv][l * 2 + 1] = abot[l]; }
  }
  __syncthreads();
  if (tid < 16) {
    float v = red[0][tid] + red[1][tid] + red[2][tid] + red[3][tid];
    partial[blk * 16 + tid] = v;   // [block][l*2 + (0=top,1=bot)]
  }
}

__global__ void finalize_kernel(const float* __restrict__ partial, float* __restrict__ out) {
  __shared__ float rr[16];
  int t = threadIdx.x;          // 256 threads: 16 pairs x 16 workers
  int p = t >> 4, k = t & 15;
  int b = p >> 3, l = p & 7;
  float top = 0.f, bot = 0.f;
  for (int m = 0; m < BLK_PER_B / 16; ++m) {     // 64 blocks each
    int blk = b * BLK_PER_B + k * (BLK_PER_B / 16) + m;
    top += partial[blk * 16 + l * 2];
    bot += partial[blk * 16 + l * 2 + 1];
  }
#pragma unroll
  for (int o = 8; o > 0; o >>= 1) {
    top += __shfl_down(top, o, 16);
    bot += __shfl_down(bot, o, 16);
  }
  if (k == 0) rr[p] = 2.f * top / fmaxf(bot, EPS);
  __syncthreads();
  if (t == 0) {
    float s = 0.f;
#pragma unroll
    for (int i = 0; i < 16; ++i) s += rr[i];
    out[0] = -s / 16.f;
  }
}

extern "C" void kernel_launch(void* const* d_in, const int* in_sizes, int n_in,
                              void* d_out, int out_size, void* d_ws, size_t ws_size,
                              hipStream_t stream) {
  const float* pred = (const float*)d_in[0];
  const float* tgt  = (const float*)d_in[1];
  float* partial = (float*)d_ws;   // NBLK*16 floats = 128 KB

  fused_kernel<<<NBLK, 256, 0, stream>>>(pred, tgt, partial);
  finalize_kernel<<<1, 256, 0, stream>>>(partial, (float*)d_out);
}

// Round 4
// 315.314 us; speedup vs baseline: 1.1481x; 1.1481x over previous
//
#include <hip/hip_runtime.h>
#include <hip/hip_fp16.h>

constexpr int Dd = 128, Hh = 128, Ww = 128;
constexpr int B_ = 2, L_ = 8;
constexpr int S_SP = Dd * Hh * Ww;          // 2097152
constexpr float CLAMP_MIN = 0.071f;
constexpr float EPS = 1e-5f;

constexpr int DCH = 8;                       // d planes per K2 block
constexpr int NDC = Dd / DCH;                // 16
constexpr int NHG = Hh / 16;                 // 8
constexpr int BLK_PER_P = NDC * NHG;         // 128 blocks per (b,l)
constexpr int NBLK2 = B_ * L_ * BLK_PER_P;   // 2048

// ---------------- K1: softmax over L + clamp -> fp16 scratch ----------------
// Thread handles 4 consecutive voxels across all 8 labels. Fully coalesced.
__global__ __launch_bounds__(256) void softmax_fp16_kernel(
    const float* __restrict__ pred, __half* __restrict__ ps) {
  const int S4 = S_SP / 4;
  int g = blockIdx.x * 256 + threadIdx.x;    // over B_*S4
  int b = g / S4;
  int s4 = g - b * S4;
  const float4* in = (const float4*)(pred + (size_t)b * L_ * S_SP) + s4;
  float v[L_][4];
#pragma unroll
  for (int l = 0; l < L_; ++l) {
    float4 t = in[(size_t)l * S4];
    v[l][0] = t.x; v[l][1] = t.y; v[l][2] = t.z; v[l][3] = t.w;
  }
#pragma unroll
  for (int c = 0; c < 4; ++c) {
    float m = v[0][c];
#pragma unroll
    for (int l = 1; l < L_; ++l) m = fmaxf(m, v[l][c]);
    float s = 0.f;
#pragma unroll
    for (int l = 0; l < L_; ++l) { v[l][c] = __expf(v[l][c] - m); s += v[l][c]; }
    float inv = 1.f / s;
#pragma unroll
    for (int l = 0; l < L_; ++l) v[l][c] = fmaxf(v[l][c] * inv, CLAMP_MIN);
  }
#pragma unroll
  for (int l = 0; l < L_; ++l) {
    __half2 h0 = __floats2half2_rn(v[l][0], v[l][1]);
    __half2 h1 = __floats2half2_rn(v[l][2], v[l][3]);
    uint2 u;
    u.x = *(unsigned*)&h0;
    u.y = *(unsigned*)&h1;
    *(uint2*)(ps + ((size_t)(b * L_ + l)) * S_SP + (size_t)s4 * 4) = u;
  }
}

// -------- K2: streaming 27-pt stencil + dice, register-rolling over d --------
// Block = (b,l, 16-row h-group, 8-plane d-chunk). Thread owns 8 w of one h row.
// No LDS / no barriers in the hot loop; w-edges via wave shuffle.
__global__ __launch_bounds__(256) void stencil_dice_kernel(
    const __half* __restrict__ ps, const float* __restrict__ pred,
    const float* __restrict__ tgt, float* __restrict__ partial) {
  int blk = blockIdx.x;
  int dc = blk & 15;
  int hg = (blk >> 4) & 7;
  int bl = blk >> 7;                 // b*L + l
  int tid = threadIdx.x;
  int wl = tid & 15, hl = tid >> 4;
  int h = hg * 16 + hl;
  int w0 = wl * 8;
  int d0 = dc * DCH;
  const __half* P = ps + (size_t)bl * S_SP;
  int hm = (h == 0) ? 1 : h - 1;
  int hp = (h == Hh - 1) ? Hh - 2 : h + 1;

  float s2m[8], s2c[8], cprev[8];
  float top = 0.f, bot = 0.f;

  for (int t = d0 - 1; t <= d0 + DCH; ++t) {
    int rt = t < 0 ? 1 : (t > Dd - 1 ? Dd - 2 : t);
    const __half* plane = P + (size_t)rt * Hh * Ww;
    float s2n[8], ctr[8];
#pragma unroll
    for (int w = 0; w < 8; ++w) s2n[w] = 0.f;
    int rows[3] = {hm, h, hp};
#pragma unroll
    for (int ri = 0; ri < 3; ++ri) {
      uint4 u = *(const uint4*)(plane + rows[ri] * Ww + w0);
      float f[8];
      __half2 a;
      a = *(__half2*)&u.x; { float2 q = __half22float2(a); f[0] = q.x; f[1] = q.y; }
      a = *(__half2*)&u.y; { float2 q = __half22float2(a); f[2] = q.x; f[3] = q.y; }
      a = *(__half2*)&u.z; { float2 q = __half22float2(a); f[4] = q.x; f[5] = q.y; }
      a = *(__half2*)&u.w; { float2 q = __half22float2(a); f[6] = q.x; f[7] = q.y; }
      float lf = __shfl_up(f[7], 1, 64);
      if (wl == 0) lf = f[1];          // w=-1 reflects to w=1
      float rg = __shfl_down(f[0], 1, 64);
      if (wl == 15) rg = f[6];         // w=128 reflects to w=126
      s2n[0] += lf + f[0] + f[1];
#pragma unroll
      for (int w = 1; w < 7; ++w) s2n[w] += f[w - 1] + f[w] + f[w + 1];
      s2n[7] += f[6] + f[7] + rg;
      if (ri == 1) {
#pragma unroll
        for (int w = 0; w < 8; ++w) ctr[w] = f[w];
      }
    }
    if (t >= d0 + 1) {
      int d = t - 1;
      size_t off = (size_t)bl * S_SP + (size_t)d * Hh * Ww + (size_t)h * Ww + w0;
      float4 p0 = *(const float4*)(pred + off);
      float4 p1 = *(const float4*)(pred + off + 4);
      float4 t0 = *(const float4*)(tgt + off);
      float4 t1 = *(const float4*)(tgt + off + 4);
      float pv[8] = {p0.x, p0.y, p0.z, p0.w, p1.x, p1.y, p1.z, p1.w};
      float tv[8] = {t0.x, t0.y, t0.z, t0.w, t1.x, t1.y, t1.z, t1.w};
#pragma unroll
      for (int w = 0; w < 8; ++w) {
        float bt = fabsf(27.f * cprev[w] - (s2m[w] + s2c[w] + s2n[w]));
        float bw = 0.5f / (bt + 0.5f);
        top += tv[w] * pv[w] * bw;
        bot += (tv[w] + pv[w]) * bw;
      }
    }
#pragma unroll
    for (int w = 0; w < 8; ++w) { s2m[w] = s2c[w]; s2c[w] = s2n[w]; cprev[w] = ctr[w]; }
  }

  // block reduce (2 scalars) -> partial[blk]
#pragma unroll
  for (int o = 32; o > 0; o >>= 1) {
    top += __shfl_down(top, o, 64);
    bot += __shfl_down(bot, o, 64);
  }
  __shared__ float st[4], sb[4];
  int lane = tid & 63, wv = tid >> 6;
  if (lane == 0) { st[wv] = top; sb[wv] = bot; }
  __syncthreads();
  if (tid == 0) {
    partial[blk * 2 + 0] = st[0] + st[1] + st[2] + st[3];
    partial[blk * 2 + 1] = sb[0] + sb[1] + sb[2] + sb[3];
  }
}

// ---------------- K3: 2048 partial pairs -> scalar ----------------
__global__ void finalize_kernel(const float* __restrict__ partial, float* __restrict__ out) {
  __shared__ float rr[16];
  int t = threadIdx.x;             // 256 = 16 pairs x 16 workers
  int p = t >> 4, k = t & 15;
  float top = 0.f, bot = 0.f;
  for (int m = 0; m < BLK_PER_P / 16; ++m) {   // 8 blocks each
    int blk = p * BLK_PER_P + k * (BLK_PER_P / 16) + m;
    top += partial[blk * 2 + 0];
    bot += partial[blk * 2 + 1];
  }
#pragma unroll
  for (int o = 8; o > 0; o >>= 1) {
    top += __shfl_down(top, o, 16);
    bot += __shfl_down(bot, o, 16);
  }
  if (k == 0) rr[p] = 2.f * top / fmaxf(bot, EPS);
  __syncthreads();
  if (t == 0) {
    float s = 0.f;
#pragma unroll
    for (int i = 0; i < 16; ++i) s += rr[i];
    out[0] = -s / 16.f;
  }
}

extern "C" void kernel_launch(void* const* d_in, const int* in_sizes, int n_in,
                              void* d_out, int out_size, void* d_ws, size_t ws_size,
                              hipStream_t stream) {
  const float* pred = (const float*)d_in[0];
  const float* tgt  = (const float*)d_in[1];
  __half* ps = (__half*)d_ws;                                  // 67 MB fp16
  float* partial = (float*)((char*)d_ws + (size_t)B_ * L_ * S_SP * sizeof(__half));

  int g1 = (B_ * (S_SP / 4)) / 256;    // 4096 blocks
  softmax_fp16_kernel<<<g1, 256, 0, stream>>>(pred, ps);
  stencil_dice_kernel<<<NBLK2, 256, 0, stream>>>(ps, pred, tgt, partial);
  finalize_kernel<<<1, 256, 0, stream>>>(partial, (float*)d_out);
}